// Round 9
// baseline (741.628 us; speedup 1.0000x reference)
//
#include <hip/hip_runtime.h>

#define NEGF (-1e30f)

namespace {

constexpr int B = 4, T = 512, L = 64, U = 65, V = 1024;

__device__ __forceinline__ float lse2(float a, float b) {
    // logaddexp; safe when one/both operands are ~-1e30 (exp underflows to 0)
    float m = fmaxf(a, b);
    float d = fminf(a, b) - m;
    return m + __logf(1.0f + __expf(d));
}

// --- DPP helpers: cross-lane without the LDS pipe (ds_permute ~120cy) ------
__device__ __forceinline__ float dpp_bcast_op_max(float x) {
    x = fmaxf(x, __int_as_float(__builtin_amdgcn_update_dpp(0, __float_as_int(x), 0xB1, 0xF, 0xF, true)));
    x = fmaxf(x, __int_as_float(__builtin_amdgcn_update_dpp(0, __float_as_int(x), 0x4E, 0xF, 0xF, true)));
    x = fmaxf(x, __int_as_float(__builtin_amdgcn_update_dpp(0, __float_as_int(x), 0x141, 0xF, 0xF, true)));
    x = fmaxf(x, __int_as_float(__builtin_amdgcn_update_dpp(0, __float_as_int(x), 0x140, 0xF, 0xF, true)));
    x = fmaxf(x, __shfl_xor(x, 16, 64));
    x = fmaxf(x, __shfl_xor(x, 32, 64));
    return x;
}
__device__ __forceinline__ float dpp_bcast_op_sum(float x) {
    x += __int_as_float(__builtin_amdgcn_update_dpp(0, __float_as_int(x), 0xB1, 0xF, 0xF, true));
    x += __int_as_float(__builtin_amdgcn_update_dpp(0, __float_as_int(x), 0x4E, 0xF, 0xF, true));
    x += __int_as_float(__builtin_amdgcn_update_dpp(0, __float_as_int(x), 0x141, 0xF, 0xF, true));
    x += __int_as_float(__builtin_amdgcn_update_dpp(0, __float_as_int(x), 0x140, 0xF, 0xF, true));
    x += __shfl_xor(x, 16, 64);
    x += __shfl_xor(x, 32, 64);
    return x;
}
__device__ __forceinline__ float dpp_shr1(float x) {
    return __int_as_float(__builtin_amdgcn_update_dpp(
        0, __float_as_int(x), 0x138, 0xF, 0xF, true));
}

// ---------------------------------------------------------------------------
// Kernel 1: persistent-wave, software-pipelined LSE.
//  * 8192 waves grid-stride over the 133k rows (~16 rows/wave). Per live row:
//    issue the NEXT row's 4x float4 loads FIRST, then reduce+store the
//    PREVIOUS row while they fly (~700cy of reduce covers HBM latency).
//    One-shot-wave-per-row (old) had a ~40% load-issue duty cycle ->
//    latency-bound at ~1.2 TB/s; this keeps 4KB in flight continuously.
//  * p[tgt] memory reload ELIMINATED: tgt is wave-uniform, so the element is
//    extracted from the in-register row via uniform selects + one __shfl.
//    (Old version had a dependent load inside the reduce -> vmcnt(0) stall.)
//  * All pipeline state is named float4s (no runtime-indexed arrays).
//  * Arithmetic (fmax tree, DPP reduce order, sum order) is IDENTICAL to the
//    previous k1 -> bit-identical lpb/lpl.
//  * Trapezoid skip unchanged: dead rows cost ~20 scalar cycles, no loads.
// ---------------------------------------------------------------------------
__global__ __launch_bounds__(256) void rna_lse_kernel(
    const float* __restrict__ logits, const int* __restrict__ targets,
    const int* __restrict__ fbank_len, const int* __restrict__ text_len,
    float* __restrict__ lpb, float* __restrict__ lpl) {
    const int lane = threadIdx.x & 63;
    const int wid  = blockIdx.x * 4 + (threadIdx.x >> 6);
    const int nw   = gridDim.x * 4;
    constexpr int TOTAL = B * T * U;

    // batch lengths in registers (wave-uniform selects, no per-row loads)
    const int f0 = fbank_len[0], f1 = fbank_len[1], f2 = fbank_len[2], f3 = fbank_len[3];
    const int x0 = text_len[0],  x1 = text_len[1],  x2 = text_len[2],  x3 = text_len[3];

    // pipeline state: previous live row (registers + metadata)
    bool   have = false;
    int    pu = 0, pt = 0, pb = 0;
    float4 c0, c1, c2, c3;

    auto reduce_store = [&](void) {
        float m = fmaxf(fmaxf(fmaxf(c0.x, c0.y), fmaxf(c0.z, c0.w)),
                  fmaxf(fmaxf(fmaxf(c1.x, c1.y), fmaxf(c1.z, c1.w)),
                  fmaxf(fmaxf(fmaxf(c2.x, c2.y), fmaxf(c2.z, c2.w)),
                        fmaxf(fmaxf(c3.x, c3.y), fmaxf(c3.z, c3.w)))));
        m = dpp_bcast_op_max(m);
        float s = __expf(c0.x - m) + __expf(c0.y - m) + __expf(c0.z - m) + __expf(c0.w - m)
                + __expf(c1.x - m) + __expf(c1.y - m) + __expf(c1.z - m) + __expf(c1.w - m)
                + __expf(c2.x - m) + __expf(c2.y - m) + __expf(c2.z - m) + __expf(c2.w - m)
                + __expf(c3.x - m) + __expf(c3.y - m) + __expf(c3.z - m) + __expf(c3.w - m);
        s = dpp_bcast_op_sum(s);
        float lse = m + __logf(s);

        if (pu < L) {
            // extract logits[row][tgt] from registers: tgt is wave-uniform
            int tgt  = targets[pb * L + pu];
            int blk  = tgt >> 8;          // which float4 bank (0..3)
            int lsrc = (tgt >> 2) & 63;   // source lane
            int comp = tgt & 3;           // component
            float4 vb = (blk == 0) ? c0 : (blk == 1) ? c1 : (blk == 2) ? c2 : c3;
            float  el = (comp == 0) ? vb.x : (comp == 1) ? vb.y : (comp == 2) ? vb.z : vb.w;
            float  ptgt = __shfl(el, lsrc, 64);
            if (lane == 0)
                lpl[(pb * U + pu + 1) * T + pt] = ptgt - lse;
        }
        if (lane == 0)
            lpb[(pb * U + pu) * T + pt] = c0.x - lse;   // element 0 = lane0.c0.x
    };

    for (int row = wid; row < TOTAL; row += nw) {
        const int u  = row % U;
        const int bt = row / U;
        const int t  = bt & (T - 1);
        const int b  = bt >> 9;
        const int fb = (b == 0) ? f0 : (b == 1) ? f1 : (b == 2) ? f2 : f3;
        const int tl = (b == 0) ? x0 : (b == 1) ? x1 : (b == 2) ? x2 : x3;
        if (t >= fb || u > tl || u > t + 1 || (tl - u) > (fb - t)) continue;

        // issue this row's loads BEFORE reducing the previous row
        const float4* p4 = (const float4*)(logits + (size_t)row * V);
        float4 n0 = p4[lane];
        float4 n1 = p4[lane + 64];
        float4 n2 = p4[lane + 128];
        float4 n3 = p4[lane + 192];

        if (have) reduce_store();

        c0 = n0; c1 = n1; c2 = n2; c3 = n3;
        pu = u; pt = t; pb = b;
        have = true;
    }
    if (have) reduce_store();
}

// ---------------------------------------------------------------------------
// Kernel 2: forward lattice DP (UNCHANGED — bracketed ≤40us).
// ---------------------------------------------------------------------------
__global__ __launch_bounds__(64, 1) void rna_dp_kernel(
    const float* __restrict__ lpb, const float* __restrict__ lpl,
    const int* __restrict__ fbank_len, const int* __restrict__ text_len,
    float* __restrict__ partial) {
    const int lane = threadIdx.x;    // 0..63
    const int b    = blockIdx.x;     // 0..3
    const int fb   = fbank_len[b];
    const int tl   = text_len[b];

    const float* pbR   = lpb + (b * U + lane) * T;
    const float* plR   = lpl + (b * U + lane) * T;
    const float* pbR64 = lpb + (b * U + 64) * T;
    const float* plR64 = lpl + (b * U + 64) * T;

    float alpha   = (lane == 0) ? 0.0f : NEGF;
    float alpha64 = NEGF;

    constexpr int G = 32;
    float cb[G], cl[G], cb64[G], cl64[G];
#pragma unroll
    for (int q = 0; q < G / 4; ++q) {
        float4 a  = *(const float4*)(pbR   + 4 * q);
        float4 c  = *(const float4*)(plR   + 4 * q);
        float4 e  = *(const float4*)(pbR64 + 4 * q);
        float4 g4 = *(const float4*)(plR64 + 4 * q);
        cb[4*q+0]=a.x;  cb[4*q+1]=a.y;  cb[4*q+2]=a.z;  cb[4*q+3]=a.w;
        cl[4*q+0]=c.x;  cl[4*q+1]=c.y;  cl[4*q+2]=c.z;  cl[4*q+3]=c.w;
        cb64[4*q+0]=e.x;  cb64[4*q+1]=e.y;  cb64[4*q+2]=e.z;  cb64[4*q+3]=e.w;
        cl64[4*q+0]=g4.x; cl64[4*q+1]=g4.y; cl64[4*q+2]=g4.z; cl64[4*q+3]=g4.w;
    }

    const int nFull = fb / G;
    for (int g = 0; g < nFull; ++g) {
        const int t0 = g * G;
        float nb[G], nl[G], nb64[G], nl64[G];
        const bool pf = (g + 1 < nFull);
        if (pf) {
            const int tn = t0 + G;
#pragma unroll
            for (int q = 0; q < G / 4; ++q) {
                float4 a  = *(const float4*)(pbR   + tn + 4 * q);
                float4 c  = *(const float4*)(plR   + tn + 4 * q);
                float4 e  = *(const float4*)(pbR64 + tn + 4 * q);
                float4 g4 = *(const float4*)(plR64 + tn + 4 * q);
                nb[4*q+0]=a.x;  nb[4*q+1]=a.y;  nb[4*q+2]=a.z;  nb[4*q+3]=a.w;
                nl[4*q+0]=c.x;  nl[4*q+1]=c.y;  nl[4*q+2]=c.z;  nl[4*q+3]=c.w;
                nb64[4*q+0]=e.x;  nb64[4*q+1]=e.y;  nb64[4*q+2]=e.z;  nb64[4*q+3]=e.w;
                nl64[4*q+0]=g4.x; nl64[4*q+1]=g4.y; nl64[4*q+2]=g4.z; nl64[4*q+3]=g4.w;
            }
        }
#pragma unroll
        for (int j = 0; j < G; ++j) {
            const int t = t0 + j;
            float ap   = dpp_shr1(alpha);
            float stay = alpha + cb[j];
            float move = (lane == 0) ? NEGF : (ap + cl[j]);
            float na   = lse2(stay, move);
            float stay64 = alpha64 + cb64[j];
            float move64 = alpha + cl64[j];
            alpha64 = lse2(stay64, move64);
            alpha   = na;
            if (lane > t + 1) alpha = NEGF;
            if (t + 1 < 64)   alpha64 = NEGF;
        }
        if (pf) {
#pragma unroll
            for (int j = 0; j < G; ++j) {
                cb[j] = nb[j]; cl[j] = nl[j]; cb64[j] = nb64[j]; cl64[j] = nl64[j];
            }
        }
    }

    for (int t = nFull * G; t < fb; ++t) {
        float bj  = pbR[t];
        float lj  = plR[t];
        float b64 = pbR64[t];
        float l64 = plR64[t];
        float ap   = dpp_shr1(alpha);
        float stay = alpha + bj;
        float move = (lane == 0) ? NEGF : (ap + lj);
        float na   = lse2(stay, move);
        float stay64 = alpha64 + b64;
        float move64 = alpha + l64;
        alpha64 = lse2(stay64, move64);
        alpha   = na;
        if (lane > t + 1) alpha = NEGF;
        if (t + 1 < 64)   alpha64 = NEGF;
    }

    float ans = (tl < 64) ? __shfl(alpha, tl, 64) : __shfl(alpha64, 63, 64);
    if (lane == 0) partial[b] = ans;
}

// ---------------------------------------------------------------------------
// Kernel 3: final mean (same summation order -> bit-identical result).
// ---------------------------------------------------------------------------
__global__ void rna_sum_kernel(const float* __restrict__ partial,
                               float* __restrict__ out) {
    out[0] = -(partial[0] + partial[1] + partial[2] + partial[3]) * (1.0f / B);
}

} // namespace

extern "C" void kernel_launch(void* const* d_in, const int* in_sizes, int n_in,
                              void* d_out, int out_size, void* d_ws, size_t ws_size,
                              hipStream_t stream) {
    const float* logits  = (const float*)d_in[0];
    const int*   targets = (const int*)d_in[1];
    const int*   fbl     = (const int*)d_in[2];
    const int*   txl     = (const int*)d_in[3];
    float* lpb     = (float*)d_ws;                 // [B][U][T]
    float* lpl     = lpb + (size_t)B * U * T;      // [B][U][T]
    float* partial = lpl + (size_t)B * U * T;      // [B]
    float* out     = (float*)d_out;

    // 2048 blocks * 4 waves = 8192 persistent waves = 32 waves/CU on 256 CUs
    rna_lse_kernel<<<2048, 256, 0, stream>>>(logits, targets, fbl, txl, lpb, lpl);
    rna_dp_kernel<<<B, 64, 0, stream>>>(lpb, lpl, fbl, txl, partial);
    rna_sum_kernel<<<1, 1, 0, stream>>>(partial, out);
}